// Round 4
// baseline (341.632 us; speedup 1.0000x reference)
//
#include <hip/hip_runtime.h>
#include <hip/hip_fp8.h>

// Problem constants (fixed by the test): M=8192, H=4096, K=H, GROUP=128.
#define MDIM 8192
#define HDIM 4096

typedef float f32x4 __attribute__((ext_vector_type(4)));
typedef long i64;

__device__ inline void gload_lds16(const void* g, void* l) {
  __builtin_amdgcn_global_load_lds(
      (const __attribute__((address_space(1))) void*)g,
      (__attribute__((address_space(3))) void*)l, 16, 0, 0);
}

// ---------------------------------------------------------------------------
// Kernel 1: y = silu(x[:, :H]) * x[:, H:]; per-(1,128) group fp8 quant.
// Writes q (fp8 bytes, [M][H]) and scales transposed st[kb][M] (f32).
// One block per row; 8 lanes per 128-group; fully coalesced float4 loads.
// ---------------------------------------------------------------------------
__global__ __launch_bounds__(256) void silu_quant_kernel(
    const float* __restrict__ x, unsigned char* __restrict__ q,
    float* __restrict__ st) {
  const int m = blockIdx.x;
  const int t = threadIdx.x;
  const int g = t >> 3;   // group 0..31
  const int i = t & 7;    // lane-in-group
  const float* xr = x + (size_t)m * (2 * HDIM);

  float v[16];
  float amax = 0.f;
#pragma unroll
  for (int j = 0; j < 4; ++j) {
    const int off = g * 128 + j * 32 + i * 4;
    f32x4 gate = *(const f32x4*)(xr + off);
    f32x4 up = *(const f32x4*)(xr + HDIM + off);
#pragma unroll
    for (int c = 0; c < 4; ++c) {
      float gg = gate[c];
      float s = gg / (1.f + expf(-gg));  // silu; -0 limit matches ref
      float val = s * up[c];
      v[j * 4 + c] = val;
      amax = fmaxf(amax, fabsf(val));
    }
  }
  // reduce amax over the 8-lane group (xor masks stay inside the group)
#pragma unroll
  for (int d = 1; d < 8; d <<= 1) amax = fmaxf(amax, __shfl_xor(amax, d, 64));
  const float scale = fmaxf(amax, 1e-12f) / 448.0f;

#pragma unroll
  for (int j = 0; j < 4; ++j) {
    unsigned int pk = 0;
#pragma unroll
    for (int c = 0; c < 4; ++c) {
      __hip_fp8_e4m3 qv(v[j * 4 + c] / scale);  // RNE onto e4m3fn grid
      pk |= ((unsigned int)qv.__x) << (8 * c);
    }
    *(unsigned int*)(q + (size_t)m * HDIM + g * 128 + j * 32 + i * 4) = pk;
  }
  if (i == 0) st[(size_t)g * MDIM + m] = scale;
}

// ---------------------------------------------------------------------------
// Kernel 2: weight f32 -> fp8 byte (exact; values already on fp8 grid),
// transposed to wt[n][k] so GEMM B-fragments read contiguous k.
// 64x64 tiles via LDS (stride 68 bytes to dodge bank conflicts).
// ---------------------------------------------------------------------------
__global__ __launch_bounds__(256) void wconv_kernel(
    const float* __restrict__ w, unsigned char* __restrict__ wt) {
  __shared__ __align__(16) unsigned char tile[64 * 68];
  const int t = threadIdx.x;
  const int n0 = (blockIdx.x & 63) * 64;
  const int k0 = (blockIdx.x >> 6) * 64;
  {
    const int r = t >> 4;
    const int c4 = (t & 15) << 2;
#pragma unroll
    for (int j = 0; j < 4; ++j) {
      const int kr = r + j * 16;
      f32x4 vv = *(const f32x4*)(w + (size_t)(k0 + kr) * HDIM + n0 + c4);
      unsigned int pk = 0;
#pragma unroll
      for (int c = 0; c < 4; ++c) {
        __hip_fp8_e4m3 qv(vv[c]);
        pk |= ((unsigned int)qv.__x) << (8 * c);
      }
      *(unsigned int*)(tile + kr * 68 + c4) = pk;
    }
  }
  __syncthreads();
  {
    const int n = t >> 4;
    const int k4 = (t & 15) << 2;
#pragma unroll
    for (int j = 0; j < 4; ++j) {
      const int nn = n + j * 16;
      unsigned int pk = 0;
#pragma unroll
      for (int c = 0; c < 4; ++c)
        pk |= ((unsigned int)tile[(k4 + c) * 68 + nn]) << (8 * c);
      *(unsigned int*)(wt + (size_t)(n0 + nn) * HDIM + k0 + k4) = pk;
    }
  }
}

// ---------------------------------------------------------------------------
// Kernel 3: block-scaled fp8 GEMM. 128x128 tile, BK=128 (== GROUP), 4 waves
// (2x2, 64x64 each, 4x4 frags of 16x16x32 fp8 MFMA). Per K-step: zero-based
// block accumulate over K=128, then acc += blk * (s_a[row] * s_w) in f32.
// LDS layout: [row][128 bytes] with 16B-chunk XOR swizzle
// (chunk_stored = chunk ^ (row&7)); global_load_lds dest stays linear, the
// source address is pre-swizzled, ds_read applies the same XOR (m201 rule 21).
// ---------------------------------------------------------------------------
__global__ __launch_bounds__(256, 2) void gemm_fp8_kernel(
    const unsigned char* __restrict__ Aq,  // [M][K] fp8
    const unsigned char* __restrict__ Bt,  // [N][K] fp8 (w transposed)
    const float* __restrict__ st,          // [32][M] act scales
    const float* __restrict__ wsc,         // [32][32] weight scales
    float* __restrict__ out) {             // [M][N] f32
  __shared__ __align__(16) unsigned char As[128 * 128];
  __shared__ __align__(16) unsigned char Bs[128 * 128];
  __shared__ __align__(16) float sas[128];

  const int t = threadIdx.x;
  const int ntile = blockIdx.x & 31;
  const int mtile = blockIdx.x >> 5;
  const int m0 = mtile * 128, n0 = ntile * 128;

  const int l = t & 63, wid = t >> 6;
  const int wm = wid >> 1, wn = wid & 1;
  const int lrow = l & 15, lhi = l >> 4;

  f32x4 acc[4][4];
#pragma unroll
  for (int a = 0; a < 4; ++a)
#pragma unroll
    for (int b = 0; b < 4; ++b) acc[a][b] = (f32x4){0.f, 0.f, 0.f, 0.f};

  // staging geometry: linear LDS pos (p*256+t)*16 -> row = p*32 + t/8,
  // stored chunk = t&7, holds logical chunk kc = (t&7) ^ (row&7).
  const int sr = t >> 3;
  const int skc = (t & 7) ^ (sr & 7);

  for (int kb = 0; kb < 32; ++kb) {
    __syncthreads();  // previous compute done before restaging
    const int kbase = kb * 128 + skc * 16;
#pragma unroll
    for (int p = 0; p < 4; ++p) {
      const int row = sr + p * 32;
      gload_lds16(Aq + (size_t)(m0 + row) * HDIM + kbase, As + (p * 256 + t) * 16);
      gload_lds16(Bt + (size_t)(n0 + row) * HDIM + kbase, Bs + (p * 256 + t) * 16);
    }
    if (t < 128) sas[t] = st[(size_t)kb * MDIM + m0 + t];
    __syncthreads();  // drains vmcnt (global_load_lds) + lgkmcnt

    const float sw = wsc[kb * 32 + ntile];

    f32x4 blk[4][4];
#pragma unroll
    for (int kk = 0; kk < 4; ++kk) {
      // fragment k position: kbyte = kk*32 + lhi*8; row&7 == lrow&7 for all frags
      const int kbyte = kk * 32 + lhi * 8;
      const int chunk = (((kbyte >> 4) ^ (lrow & 7)) << 4) + (kbyte & 15);
      i64 af[4], bf[4];
#pragma unroll
      for (int mi = 0; mi < 4; ++mi) {
        const int row = wm * 64 + mi * 16 + lrow;
        af[mi] = *(const i64*)(As + row * 128 + chunk);
      }
#pragma unroll
      for (int ni = 0; ni < 4; ++ni) {
        const int row = wn * 64 + ni * 16 + lrow;
        bf[ni] = *(const i64*)(Bs + row * 128 + chunk);
      }
#pragma unroll
      for (int mi = 0; mi < 4; ++mi)
#pragma unroll
        for (int ni = 0; ni < 4; ++ni) {
          f32x4 cin = (kk == 0) ? (f32x4){0.f, 0.f, 0.f, 0.f} : blk[mi][ni];
          blk[mi][ni] =
              __builtin_amdgcn_mfma_f32_16x16x32_fp8_fp8(af[mi], bf[ni], cin, 0, 0, 0);
        }
    }
    // apply per-row act scale * per-block weight scale
#pragma unroll
    for (int mi = 0; mi < 4; ++mi) {
      f32x4 sa = *(const f32x4*)(sas + wm * 64 + mi * 16 + lhi * 4);
      f32x4 sm;
#pragma unroll
      for (int r = 0; r < 4; ++r) sm[r] = sa[r] * sw;
#pragma unroll
      for (int ni = 0; ni < 4; ++ni)
#pragma unroll
        for (int r = 0; r < 4; ++r)
          acc[mi][ni][r] = fmaf(blk[mi][ni][r], sm[r], acc[mi][ni][r]);
    }
  }

  // epilogue: C row = lhi*4 + r, col = lrow (dtype-independent layout)
#pragma unroll
  for (int mi = 0; mi < 4; ++mi)
#pragma unroll
    for (int r = 0; r < 4; ++r) {
      const int grow = m0 + wm * 64 + mi * 16 + lhi * 4 + r;
      float* orow = out + (size_t)grow * HDIM + n0 + wn * 64 + lrow;
#pragma unroll
      for (int ni = 0; ni < 4; ++ni) orow[ni * 16] = acc[mi][ni][r];
    }
}

// ---------------------------------------------------------------------------
extern "C" void kernel_launch(void* const* d_in, const int* in_sizes, int n_in,
                              void* d_out, int out_size, void* d_ws, size_t ws_size,
                              hipStream_t stream) {
  const float* x = (const float*)d_in[0];       // [8192][8192]
  const float* wq = (const float*)d_in[1];      // [4096][4096]
  const float* wsc = (const float*)d_in[2];     // [32][32]
  float* out = (float*)d_out;                   // [8192][4096]

  unsigned char* q = (unsigned char*)d_ws;                       // 32 MiB
  unsigned char* wt = q + (size_t)MDIM * HDIM;                   // 16 MiB
  float* st = (float*)(wt + (size_t)HDIM * HDIM);                // 1 MiB

  silu_quant_kernel<<<MDIM, 256, 0, stream>>>(x, q, st);
  wconv_kernel<<<(HDIM / 64) * (HDIM / 64), 256, 0, stream>>>(wq, wt);
  gemm_fp8_kernel<<<(MDIM / 128) * (HDIM / 128), 256, 0, stream>>>(q, wt, st, wsc, out);
}